// Round 1
// baseline (1119.014 us; speedup 1.0000x reference)
//
#include <hip/hip_runtime.h>
#include <hip/hip_bf16.h>

typedef unsigned short us8 __attribute__((ext_vector_type(8)));

#define BB 2048
#define NN 64
#define CIN 128
#define CO 256
#define KWIN 3
#define EE 256
#define NE 320            // E + N (self loops)
#define EPSBN 1e-5f

static __device__ __forceinline__ float bf2f(unsigned short u) {
    return __uint_as_float(((unsigned int)u) << 16);
}

// ---------------- kernel 1: edge preprocessing (deterministic counting sort by dst) ----------------
__global__ __launch_bounds__(320) void k_setup(const int* __restrict__ ei,
                                               int* __restrict__ srcS,
                                               float* __restrict__ normS,
                                               int* __restrict__ rowstart) {
    __shared__ int s_src[NE], s_dst[NE], s_deg[NN], s_rs[NN + 1];
    __shared__ float s_dinv[NN];
    const int t = threadIdx.x;
    if (t < NN) s_deg[t] = 0;
    __syncthreads();
    int src, dst;
    if (t < EE) { src = ei[t]; dst = ei[EE + t]; }
    else        { src = t - EE; dst = t - EE; }
    s_src[t] = src; s_dst[t] = dst;
    atomicAdd(&s_deg[dst], 1);
    __syncthreads();
    if (t < NN) s_dinv[t] = rsqrtf((float)s_deg[t]);   // deg >= 1 (self loop)
    if (t <= NN) {
        int a = 0;
        for (int m = 0; m < t; ++m) a += s_deg[m];
        s_rs[t] = a;
    }
    __syncthreads();
    {
        int rank = 0;
        for (int e = 0; e < NE; ++e)
            rank += (s_dst[e] == dst && e < t) ? 1 : 0;   // deterministic rank
        const int pos = s_rs[dst] + rank;
        srcS[pos]  = src;
        normS[pos] = s_dinv[src] * s_dinv[dst];
    }
    if (t <= NN) rowstart[t] = s_rs[t];
}

// ---------------- kernel 2: per-batch xW GEMM + GCN aggregation -> x_gcn (bf16) ----------------
__global__ __launch_bounds__(256) void k_gcn(const float* __restrict__ x,
                                             const float* __restrict__ W,
                                             const float* __restrict__ bgcn,
                                             const int* __restrict__ srcS,
                                             const float* __restrict__ normS,
                                             const int* __restrict__ rowstart,
                                             __hip_bfloat16* __restrict__ xgcn) {
    __shared__ float s_x[NN][CIN];             // 32 KB
    __shared__ __hip_bfloat16 s_xw[NN][CO];    // 32 KB
    __shared__ int s_srcS[NE], s_rs[NN + 1];
    __shared__ float s_normS[NE];
    const int b = blockIdx.x, tid = threadIdx.x;

    const float4* xb = (const float4*)(x + (size_t)b * NN * CIN);
    float4* sx4 = (float4*)(&s_x[0][0]);
#pragma unroll
    for (int i = 0; i < 8; ++i) sx4[tid + 256 * i] = xb[tid + 256 * i];
    for (int i = tid; i < NE; i += 256) { s_srcS[i] = srcS[i]; s_normS[i] = normS[i]; }
    if (tid <= NN) s_rs[tid] = rowstart[tid];
    __syncthreads();

    // thread owns output column c = tid, all 64 nodes in registers
    float acc[NN];
#pragma unroll
    for (int n = 0; n < NN; ++n) acc[n] = 0.f;
    for (int k = 0; k < CIN; k += 4) {
        const float w0 = W[(k + 0) * CO + tid];
        const float w1 = W[(k + 1) * CO + tid];
        const float w2 = W[(k + 2) * CO + tid];
        const float w3 = W[(k + 3) * CO + tid];
#pragma unroll
        for (int n = 0; n < NN; ++n) {
            const float4 xv = *(const float4*)&s_x[n][k];
            acc[n] += xv.x * w0 + xv.y * w1 + xv.z * w2 + xv.w * w3;
        }
    }
#pragma unroll
    for (int n = 0; n < NN; ++n) s_xw[n][tid] = __float2bfloat16(acc[n]);
    __syncthreads();

    const float bg = bgcn[tid];
    for (int n = 0; n < NN; ++n) {
        float a = bg;
        const int e1 = s_rs[n + 1];
        for (int e = s_rs[n]; e < e1; ++e)
            a += s_normS[e] * __bfloat162float(s_xw[s_srcS[e]][tid]);
        xgcn[((size_t)b * NN + n) * CO + tid] = __float2bfloat16(a);
    }
}

// ---------------- kernel 3: transpose w_conv [o][i][k] -> W2[(k*256+i)][o] (bf16) ----------------
__global__ __launch_bounds__(256) void k_w2(const float* __restrict__ wconv,
                                            __hip_bfloat16* __restrict__ W2) {
    const int idx = blockIdx.x * 256 + threadIdx.x;   // q*256 + o, q = kk*256 + i
    const int o = idx & 255, q = idx >> 8;
    const int kk = q >> 8, i = q & 255;
    W2[idx] = __float2bfloat16(wconv[(o * CO + i) * KWIN + kk]);
}

// ---------------- kernel 4: conv1d-as-GEMM (fp32, tiled) + bias + BN partial sums ----------------
#define CT 128    // t-tile
#define COT 128   // o-tile
#define SA_STR 21
#define SB_STR 132

__global__ __launch_bounds__(256) void k_conv(const __hip_bfloat16* __restrict__ xgcn,
                                              const __hip_bfloat16* __restrict__ W2,
                                              const float* __restrict__ bconv,
                                              float* __restrict__ y,
                                              float* __restrict__ partials) {
    const int tt = blockIdx.x, ot = blockIdx.y, n = blockIdx.z;
    const int tid = threadIdx.x;
    const int tx = tid & 15, ty = tid >> 4;
    const int t0 = tt * CT, o0 = ot * COT;

    __shared__ float sA[CT][SA_STR];
    __shared__ float sB[16][SB_STR];
    __shared__ float sred[16][COT];

    float acc[8][8];
#pragma unroll
    for (int i = 0; i < 8; ++i)
#pragma unroll
        for (int j = 0; j < 8; ++j) acc[i][j] = 0.f;

    const int arow = tid >> 1, ahalf = (tid & 1) * 8;
    const int brow = tid >> 4, bcol = (tid & 15) * 8;

    for (int q0 = 0; q0 < CO * KWIN; q0 += 16) {
        const int kk = q0 >> 8, i0 = q0 & 255;
        // A chunk: A[t][q] = xgcn[t + kk - 1][n][i], zero-padded at ends
        {
            const int tg = t0 + arow + kk - 1;
            if ((unsigned)tg < (unsigned)BB) {
                const us8 v = *(const us8*)((const unsigned short*)xgcn + ((size_t)tg * NN + n) * CO + i0 + ahalf);
#pragma unroll
                for (int j = 0; j < 8; ++j) sA[arow][ahalf + j] = bf2f(v[j]);
            } else {
#pragma unroll
                for (int j = 0; j < 8; ++j) sA[arow][ahalf + j] = 0.f;
            }
        }
        // B chunk
        {
            const us8 v = *(const us8*)((const unsigned short*)W2 + (size_t)(q0 + brow) * CO + o0 + bcol);
#pragma unroll
            for (int j = 0; j < 8; ++j) sB[brow][bcol + j] = bf2f(v[j]);
        }
        __syncthreads();
#pragma unroll
        for (int kq = 0; kq < 16; ++kq) {
            float a[8], bb[8];
#pragma unroll
            for (int i = 0; i < 8; ++i) a[i] = sA[ty * 8 + i][kq];
#pragma unroll
            for (int j = 0; j < 8; ++j) bb[j] = sB[kq][tx + j * 16];
#pragma unroll
            for (int i = 0; i < 8; ++i)
#pragma unroll
                for (int j = 0; j < 8; ++j) acc[i][j] += a[i] * bb[j];
        }
        __syncthreads();
    }

    // epilogue: +bias, write y (=d_out scratch), per-column partial sums
    float bc[8], s1[8], s2[8];
#pragma unroll
    for (int j = 0; j < 8; ++j) { bc[j] = bconv[o0 + tx + j * 16]; s1[j] = 0.f; s2[j] = 0.f; }
#pragma unroll
    for (int i = 0; i < 8; ++i) {
        const int t = t0 + ty * 8 + i;
        float* dst = y + ((size_t)t * NN + n) * CO + o0 + tx;
#pragma unroll
        for (int j = 0; j < 8; ++j) {
            const float v = acc[i][j] + bc[j];
            dst[j * 16] = v;
            s1[j] += v;
            s2[j] += v * v;
        }
    }
    // deterministic in-block reduction over ty, write per-block partials
#pragma unroll
    for (int j = 0; j < 8; ++j) sred[ty][tx + j * 16] = s1[j];
    __syncthreads();
    const int pid = (n * 2 + ot) * 16 + tt;
    float* pb = partials + (size_t)pid * (COT * 2);
    if (tid < COT) {
        float a = 0.f;
        for (int r = 0; r < 16; ++r) a += sred[r][tid];
        pb[tid * 2] = a;
    }
    __syncthreads();
#pragma unroll
    for (int j = 0; j < 8; ++j) sred[ty][tx + j * 16] = s2[j];
    __syncthreads();
    if (tid < COT) {
        float a = 0.f;
        for (int r = 0; r < 16; ++r) a += sred[r][tid];
        pb[tid * 2 + 1] = a;
    }
}

// ---------------- kernel 5: reduce BN partials -> scale/shift per channel ----------------
__global__ __launch_bounds__(256) void k_bnstats(const float* __restrict__ partials,
                                                 const float* __restrict__ gamma,
                                                 const float* __restrict__ beta,
                                                 float* __restrict__ scl,
                                                 float* __restrict__ shf) {
    const int o = blockIdx.x, tid = threadIdx.x;
    const int ot = o >> 7, c = o & 127;
    float s1 = 0.f, s2 = 0.f;
    for (int i = tid; i < 1024; i += 256) {        // 64 n * 16 tt blocks cover this channel
        const int nn = i >> 4, tt = i & 15;
        const float* p = partials + ((size_t)((nn * 2 + ot) * 16 + tt)) * 256 + c * 2;
        s1 += p[0]; s2 += p[1];
    }
    __shared__ float r1[256], r2[256];
    r1[tid] = s1; r2[tid] = s2;
    __syncthreads();
    for (int s = 128; s > 0; s >>= 1) {
        if (tid < s) { r1[tid] += r1[tid + s]; r2[tid] += r2[tid + s]; }
        __syncthreads();
    }
    if (tid == 0) {
        const float inv = 1.f / (float)((size_t)BB * NN);
        const float mean = r1[0] * inv;
        const float var  = r2[0] * inv - mean * mean;
        const float sc = gamma[o] * rsqrtf(var + EPSBN);
        scl[o] = sc;
        shf[o] = beta[o] - mean * sc;
    }
}

// ---------------- kernel 6: in-place BN apply + ReLU ----------------
__global__ __launch_bounds__(256) void k_apply(float* __restrict__ y,
                                               const float* __restrict__ scl,
                                               const float* __restrict__ shf) {
    __shared__ float ssc[CO], ssh[CO];
    const int tid = threadIdx.x;
    ssc[tid] = scl[tid]; ssh[tid] = shf[tid];
    __syncthreads();
    const size_t total4 = (size_t)BB * NN * CO / 4;
    float4* y4 = (float4*)y;
    for (size_t i = (size_t)blockIdx.x * 256 + tid; i < total4; i += (size_t)gridDim.x * 256) {
        float4 v = y4[i];
        const int ob = (int)((i * 4) & (CO - 1));
        v.x = fmaxf(0.f, v.x * ssc[ob]     + ssh[ob]);
        v.y = fmaxf(0.f, v.y * ssc[ob + 1] + ssh[ob + 1]);
        v.z = fmaxf(0.f, v.z * ssc[ob + 2] + ssh[ob + 2]);
        v.w = fmaxf(0.f, v.w * ssc[ob + 3] + ssh[ob + 3]);
        y4[i] = v;
    }
}

extern "C" void kernel_launch(void* const* d_in, const int* in_sizes, int n_in,
                              void* d_out, int out_size, void* d_ws, size_t ws_size,
                              hipStream_t stream) {
    const float* x     = (const float*)d_in[0];
    const float* W     = (const float*)d_in[1];
    const float* bgcn  = (const float*)d_in[2];
    const float* wconv = (const float*)d_in[3];
    const float* bconv = (const float*)d_in[4];
    const float* gamma = (const float*)d_in[5];
    const float* beta  = (const float*)d_in[6];
    const int*   ei    = (const int*)d_in[7];
    float* out = (float*)d_out;

    char* ws = (char*)d_ws;
    size_t off = 0;
    __hip_bfloat16* xgcn = (__hip_bfloat16*)(ws + off); off += (size_t)BB * NN * CO * 2;   // 64 MiB
    __hip_bfloat16* W2   = (__hip_bfloat16*)(ws + off); off += (size_t)CO * KWIN * CO * 2; // 384 KiB
    int*   srcS  = (int*)(ws + off);   off += 512 * 4;
    float* normS = (float*)(ws + off); off += 512 * 4;
    int*   rowst = (int*)(ws + off);   off += 128 * 4;
    float* partials = (float*)(ws + off); off += (size_t)2048 * 256 * 4;                   // 2 MiB
    float* scl = (float*)(ws + off); off += 256 * 4;
    float* shf = (float*)(ws + off); off += 256 * 4;

    k_setup<<<1, 320, 0, stream>>>(ei, srcS, normS, rowst);
    k_w2<<<768, 256, 0, stream>>>(wconv, W2);
    k_gcn<<<BB, 256, 0, stream>>>(x, W, bgcn, srcS, normS, rowst, xgcn);
    k_conv<<<dim3(16, 2, 64), 256, 0, stream>>>(xgcn, W2, bconv, out, partials);
    k_bnstats<<<256, 256, 0, stream>>>(partials, gamma, beta, scl, shf);
    k_apply<<<2048, 256, 0, stream>>>(out, scl, shf);
}

// Round 2
// 467.595 us; speedup vs baseline: 2.3931x; 2.3931x over previous
//
#include <hip/hip_runtime.h>
#include <hip/hip_bf16.h>

typedef __attribute__((ext_vector_type(8))) unsigned short us8;
typedef __attribute__((ext_vector_type(8))) short short8;
typedef __attribute__((ext_vector_type(4))) float f32x4;

#define BB 2048
#define NN 64
#define CIN 128
#define CO 256
#define KWIN 3
#define EE 256
#define NE 320            // E + N (self loops)
#define EPSBN 1e-5f

static __device__ __forceinline__ float bf2f(unsigned short u) {
    return __uint_as_float(((unsigned int)u) << 16);
}

static __device__ __forceinline__ void gload_lds16(const unsigned short* g, unsigned short* l) {
    __builtin_amdgcn_global_load_lds(
        (const __attribute__((address_space(1))) unsigned int*)g,
        (__attribute__((address_space(3))) unsigned int*)l,
        16, 0, 0);
}

// ---------------- kernel 1: edge preprocessing (deterministic counting sort by dst) ----------------
__global__ __launch_bounds__(320) void k_setup(const int* __restrict__ ei,
                                               int* __restrict__ srcS,
                                               float* __restrict__ normS,
                                               int* __restrict__ rowstart) {
    __shared__ int s_src[NE], s_dst[NE], s_deg[NN], s_rs[NN + 1];
    __shared__ float s_dinv[NN];
    const int t = threadIdx.x;
    if (t < NN) s_deg[t] = 0;
    __syncthreads();
    int src, dst;
    if (t < EE) { src = ei[t]; dst = ei[EE + t]; }
    else        { src = t - EE; dst = t - EE; }
    s_src[t] = src; s_dst[t] = dst;
    atomicAdd(&s_deg[dst], 1);
    __syncthreads();
    if (t < NN) s_dinv[t] = rsqrtf((float)s_deg[t]);   // deg >= 1 (self loop)
    if (t <= NN) {
        int a = 0;
        for (int m = 0; m < t; ++m) a += s_deg[m];
        s_rs[t] = a;
    }
    __syncthreads();
    {
        int rank = 0;
        for (int e = 0; e < NE; ++e)
            rank += (s_dst[e] == dst && e < t) ? 1 : 0;   // deterministic rank
        const int pos = s_rs[dst] + rank;
        srcS[pos]  = src;
        normS[pos] = s_dinv[src] * s_dinv[dst];
    }
    if (t <= NN) rowstart[t] = s_rs[t];
}

// ---------------- kernel 2: per-batch xW GEMM + GCN aggregation -> x_gcn (bf16) ----------------
__global__ __launch_bounds__(256) void k_gcn(const float* __restrict__ x,
                                             const float* __restrict__ W,
                                             const float* __restrict__ bgcn,
                                             const int* __restrict__ srcS,
                                             const float* __restrict__ normS,
                                             const int* __restrict__ rowstart,
                                             __hip_bfloat16* __restrict__ xgcn) {
    __shared__ float s_x[NN][CIN];             // 32 KB
    __shared__ __hip_bfloat16 s_xw[NN][CO];    // 32 KB
    __shared__ int s_srcS[NE], s_rs[NN + 1];
    __shared__ float s_normS[NE];
    const int b = blockIdx.x, tid = threadIdx.x;

    const float4* xb = (const float4*)(x + (size_t)b * NN * CIN);
    float4* sx4 = (float4*)(&s_x[0][0]);
#pragma unroll
    for (int i = 0; i < 8; ++i) sx4[tid + 256 * i] = xb[tid + 256 * i];
    for (int i = tid; i < NE; i += 256) { s_srcS[i] = srcS[i]; s_normS[i] = normS[i]; }
    if (tid <= NN) s_rs[tid] = rowstart[tid];
    __syncthreads();

    // thread owns output column c = tid, all 64 nodes in registers
    float acc[NN];
#pragma unroll
    for (int n = 0; n < NN; ++n) acc[n] = 0.f;
    for (int k = 0; k < CIN; k += 4) {
        const float w0 = W[(k + 0) * CO + tid];
        const float w1 = W[(k + 1) * CO + tid];
        const float w2 = W[(k + 2) * CO + tid];
        const float w3 = W[(k + 3) * CO + tid];
#pragma unroll
        for (int n = 0; n < NN; ++n) {
            const float4 xv = *(const float4*)&s_x[n][k];
            acc[n] += xv.x * w0 + xv.y * w1 + xv.z * w2 + xv.w * w3;
        }
    }
#pragma unroll
    for (int n = 0; n < NN; ++n) s_xw[n][tid] = __float2bfloat16(acc[n]);
    __syncthreads();

    const float bg = bgcn[tid];
    for (int n = 0; n < NN; ++n) {
        float a = bg;
        const int e1 = s_rs[n + 1];
        for (int e = s_rs[n]; e < e1; ++e)
            a += s_normS[e] * __bfloat162float(s_xw[s_srcS[e]][tid]);
        xgcn[((size_t)b * NN + n) * CO + tid] = __float2bfloat16(a);
    }
}

// ---------------- kernel 3: w_conv [o][i][k] -> W2t[o][q], q = kk*256 + i (bf16, row-major K) ----------------
__global__ __launch_bounds__(256) void k_w2t(const float* __restrict__ wconv,
                                             __hip_bfloat16* __restrict__ W2t) {
    const int idx = blockIdx.x * 256 + threadIdx.x;   // o*768 + q
    const int o = idx / 768, q = idx - o * 768;
    const int kk = q >> 8, i = q & 255;
    W2t[idx] = __float2bfloat16(wconv[(o * CO + i) * KWIN + kk]);
}

// ---------------- kernel 4: conv1d-as-GEMM, bf16 MFMA (m97 structure) + bias + BN partials ----------------
// Per n: C[t][o] = sum_q A[t][q] * B[o][q], A[t][kk*256+i] = xgcn[t+kk-1][n][i], B = W2t.
// Tile 128(t) x 128(o), BK=64, 4 waves 2x2, each wave 64x64 via 4x4 frags of 16x16x32.
__global__ __launch_bounds__(256) void k_conv(const __hip_bfloat16* __restrict__ xgcn_,
                                              const __hip_bfloat16* __restrict__ W2t_,
                                              const float* __restrict__ bconv,
                                              float* __restrict__ y,
                                              float* __restrict__ partials) {
    __shared__ unsigned short sA[128 * 64];   // 16 KB, [row t][64 k], XOR-swizzled
    __shared__ unsigned short sB[128 * 64];   // 16 KB, [row o][64 k], XOR-swizzled
    const unsigned short* xgcn = (const unsigned short*)xgcn_;
    const unsigned short* W2t  = (const unsigned short*)W2t_;

    const int tt = blockIdx.x, ot = blockIdx.y, n = blockIdx.z;
    const int tid = threadIdx.x;
    const int lane = tid & 63, wid = tid >> 6;
    const int t0 = tt * 128, o0 = ot * 128;
    const int wm0 = (wid >> 1) * 64, wn0 = (wid & 1) * 64;
    const int lhi = lane >> 4, llo = lane & 15;

    f32x4 acc[4][4];
#pragma unroll
    for (int m = 0; m < 4; ++m)
#pragma unroll
        for (int nn = 0; nn < 4; ++nn) acc[m][nn] = (f32x4){0.f, 0.f, 0.f, 0.f};

    // staging: wave w covers rows [w*32, w*32+32), 4 issues of 8 rows; lane -> (row += lane>>3, col (lane&7)*8)
    // LDS dest is LINEAR (wave-uniform base + lane*16); global source col is pre-XOR-swizzled (rule #21)
    const int srsub = lane >> 3;                              // row within 8-row issue (== row&7)
    const int scol  = (((lane & 7) ^ srsub) << 3);            // inverse-swizzled source col (elements)

    for (int kc = 0; kc < 12; ++kc) {
        const int kk = kc >> 2;                // conv tap
        const int i0 = (kc & 3) * 64;          // input-channel offset
        const int q0 = kc * 64;                // flat K offset
        // ---- stage A (xgcn rows t0-1+kk .. ) ----
#pragma unroll
        for (int iss = 0; iss < 4; ++iss) {
            const int row = wid * 32 + iss * 8 + srsub;
            int tg = t0 + row + kk - 1;
            tg = min(max(tg, 0), BB - 1);      // clamped; bad rows zeroed below
            gload_lds16(xgcn + ((size_t)tg * NN + n) * CO + i0 + scol,
                        sA + (wid * 32 + iss * 8) * 64);
        }
        // ---- stage B (W2t rows o0..o0+127) ----
#pragma unroll
        for (int iss = 0; iss < 4; ++iss) {
            const int row = wid * 32 + iss * 8 + srsub;
            gload_lds16(W2t + (size_t)(o0 + row) * (CO * KWIN) + q0 + scol,
                        sB + (wid * 32 + iss * 8) * 64);
        }
        __syncthreads();   // drains vmcnt(0): stage complete
        // ---- halo fixup: t=-1 (tt==0,kk==0) / t=2048 (tt==15,kk==2) rows must be zero ----
        if ((tt == 0 && kc < 4) || (tt == 15 && kc >= 8)) {   // block-uniform condition
            const int zr = (tt == 0) ? 0 : 127;
            if (tid < 8) *(uint4*)&sA[zr * 64 + tid * 8] = make_uint4(0u, 0u, 0u, 0u);
            __syncthreads();
        }
        // ---- MFMA over the 64-wide K chunk (2 sub-steps of 32) ----
#pragma unroll
        for (int s = 0; s < 2; ++s) {
            const int cu = s * 32 + lhi * 8;   // k-element offset within chunk
            short8 af[4], bf[4];
#pragma unroll
            for (int m = 0; m < 4; ++m) {
                const int row = wm0 + m * 16 + llo;
                af[m] = *(const short8*)&sA[row * 64 + (cu ^ ((row & 7) << 3))];
            }
#pragma unroll
            for (int nn = 0; nn < 4; ++nn) {
                const int row = wn0 + nn * 16 + llo;
                bf[nn] = *(const short8*)&sB[row * 64 + (cu ^ ((row & 7) << 3))];
            }
#pragma unroll
            for (int m = 0; m < 4; ++m)
#pragma unroll
                for (int nn = 0; nn < 4; ++nn)
                    acc[m][nn] = __builtin_amdgcn_mfma_f32_16x16x32_bf16(af[m], bf[nn], acc[m][nn], 0, 0, 0);
        }
        __syncthreads();   // all waves done reading before next stage overwrites
    }

    // ---- epilogue: +bias, store y, per-block BN partial sums (deterministic) ----
    // C/D layout (m89/m91): col = lane&15, row = (lane>>4)*4 + reg
    float bc[4], s1v[4], s2v[4];
#pragma unroll
    for (int nn = 0; nn < 4; ++nn) {
        bc[nn] = bconv[o0 + wn0 + nn * 16 + llo];
        s1v[nn] = 0.f; s2v[nn] = 0.f;
    }
#pragma unroll
    for (int m = 0; m < 4; ++m) {
#pragma unroll
        for (int reg = 0; reg < 4; ++reg) {
            const int trow = t0 + wm0 + m * 16 + lhi * 4 + reg;
            float* dst = y + ((size_t)trow * NN + n) * CO + o0 + wn0 + llo;
#pragma unroll
            for (int nn = 0; nn < 4; ++nn) {
                const float v = acc[m][nn][reg] + bc[nn];
                dst[nn * 16] = v;
                s1v[nn] += v;
                s2v[nn] += v * v;
            }
        }
    }
    // reduce 8 row-groups x 128 cols in LDS (reuse sA; final K-loop barrier already passed)
    float* sred1 = (float*)sA;          // [8][128]
    float* sred2 = sred1 + 1024;        // [8][128]
    const int rg = (wid >> 1) * 4 + lhi;
#pragma unroll
    for (int nn = 0; nn < 4; ++nn) {
        const int cl = wn0 + nn * 16 + llo;
        sred1[rg * 128 + cl] = s1v[nn];
        sred2[rg * 128 + cl] = s2v[nn];
    }
    __syncthreads();
    if (tid < 128) {
        float a = 0.f, b2 = 0.f;
#pragma unroll
        for (int r = 0; r < 8; ++r) { a += sred1[r * 128 + tid]; b2 += sred2[r * 128 + tid]; }
        float* pb = partials + (size_t)((n * 2 + ot) * 16 + tt) * 256;
        pb[tid * 2]     = a;
        pb[tid * 2 + 1] = b2;
    }
}

// ---------------- kernel 5: reduce BN partials -> scale/shift per channel ----------------
__global__ __launch_bounds__(256) void k_bnstats(const float* __restrict__ partials,
                                                 const float* __restrict__ gamma,
                                                 const float* __restrict__ beta,
                                                 float* __restrict__ scl,
                                                 float* __restrict__ shf) {
    const int o = blockIdx.x, tid = threadIdx.x;
    const int ot = o >> 7, c = o & 127;
    float s1 = 0.f, s2 = 0.f;
    for (int i = tid; i < 1024; i += 256) {        // 64 n * 16 tt blocks cover this channel
        const int nn = i >> 4, tt = i & 15;
        const float* p = partials + ((size_t)((nn * 2 + ot) * 16 + tt)) * 256 + c * 2;
        s1 += p[0]; s2 += p[1];
    }
    __shared__ float r1[256], r2[256];
    r1[tid] = s1; r2[tid] = s2;
    __syncthreads();
    for (int s = 128; s > 0; s >>= 1) {
        if (tid < s) { r1[tid] += r1[tid + s]; r2[tid] += r2[tid + s]; }
        __syncthreads();
    }
    if (tid == 0) {
        const float inv = 1.f / (float)((size_t)BB * NN);
        const float mean = r1[0] * inv;
        const float var  = r2[0] * inv - mean * mean;
        const float sc = gamma[o] * rsqrtf(var + EPSBN);
        scl[o] = sc;
        shf[o] = beta[o] - mean * sc;
    }
}

// ---------------- kernel 6: in-place BN apply + ReLU ----------------
__global__ __launch_bounds__(256) void k_apply(float* __restrict__ y,
                                               const float* __restrict__ scl,
                                               const float* __restrict__ shf) {
    __shared__ float ssc[CO], ssh[CO];
    const int tid = threadIdx.x;
    ssc[tid] = scl[tid]; ssh[tid] = shf[tid];
    __syncthreads();
    const size_t total4 = (size_t)BB * NN * CO / 4;
    float4* y4 = (float4*)y;
    for (size_t i = (size_t)blockIdx.x * 256 + tid; i < total4; i += (size_t)gridDim.x * 256) {
        float4 v = y4[i];
        const int ob = (int)((i * 4) & (CO - 1));
        v.x = fmaxf(0.f, v.x * ssc[ob]     + ssh[ob]);
        v.y = fmaxf(0.f, v.y * ssc[ob + 1] + ssh[ob + 1]);
        v.z = fmaxf(0.f, v.z * ssc[ob + 2] + ssh[ob + 2]);
        v.w = fmaxf(0.f, v.w * ssc[ob + 3] + ssh[ob + 3]);
        y4[i] = v;
    }
}

extern "C" void kernel_launch(void* const* d_in, const int* in_sizes, int n_in,
                              void* d_out, int out_size, void* d_ws, size_t ws_size,
                              hipStream_t stream) {
    const float* x     = (const float*)d_in[0];
    const float* W     = (const float*)d_in[1];
    const float* bgcn  = (const float*)d_in[2];
    const float* wconv = (const float*)d_in[3];
    const float* bconv = (const float*)d_in[4];
    const float* gamma = (const float*)d_in[5];
    const float* beta  = (const float*)d_in[6];
    const int*   ei    = (const int*)d_in[7];
    float* out = (float*)d_out;

    char* ws = (char*)d_ws;
    size_t off = 0;
    __hip_bfloat16* xgcn = (__hip_bfloat16*)(ws + off); off += (size_t)BB * NN * CO * 2;   // 64 MiB
    __hip_bfloat16* W2t  = (__hip_bfloat16*)(ws + off); off += (size_t)CO * KWIN * CO * 2; // 384 KiB
    int*   srcS  = (int*)(ws + off);   off += 512 * 4;
    float* normS = (float*)(ws + off); off += 512 * 4;
    int*   rowst = (int*)(ws + off);   off += 128 * 4;
    float* partials = (float*)(ws + off); off += (size_t)2048 * 256 * 4;                   // 2 MiB
    float* scl = (float*)(ws + off); off += 256 * 4;
    float* shf = (float*)(ws + off); off += 256 * 4;

    k_setup<<<1, 320, 0, stream>>>(ei, srcS, normS, rowst);
    k_w2t<<<768, 256, 0, stream>>>(wconv, W2t);
    k_gcn<<<BB, 256, 0, stream>>>(x, W, bgcn, srcS, normS, rowst, xgcn);
    k_conv<<<dim3(16, 2, 64), 256, 0, stream>>>(xgcn, W2t, bconv, out, partials);
    k_bnstats<<<256, 256, 0, stream>>>(partials, gamma, beta, scl, shf);
    k_apply<<<2048, 256, 0, stream>>>(out, scl, shf);
}

// Round 3
// 167.483 us; speedup vs baseline: 6.6814x; 2.7919x over previous
//
#include <hip/hip_runtime.h>
#include <hip/hip_bf16.h>

typedef __attribute__((ext_vector_type(8))) unsigned short us8;
typedef __attribute__((ext_vector_type(8))) short short8;
typedef __attribute__((ext_vector_type(4))) float f32x4;

#define BB 2048
#define NN 64
#define CIN 128
#define CO 256
#define KWIN 3
#define EE 256
#define NE 320            // E + N (self loops)
#define EPSBN 1e-5f

static __device__ __forceinline__ void gload_lds16(const unsigned short* g, unsigned short* l) {
    __builtin_amdgcn_global_load_lds(
        (const __attribute__((address_space(1))) unsigned int*)g,
        (__attribute__((address_space(3))) unsigned int*)l,
        16, 0, 0);
}

static __device__ __forceinline__ unsigned short f2bfu(float f) {
    unsigned int u = __float_as_uint(f);
    u = (u + 0x7FFFu + ((u >> 16) & 1u)) >> 16;   // RN-even
    return (unsigned short)u;
}

// ---------------- kernel 1: dense normalized adjacency Ahat[dst][src] (bf16), deterministic ----------------
__global__ __launch_bounds__(320) void k_setup(const int* __restrict__ ei,
                                               __hip_bfloat16* __restrict__ Ahat) {
    __shared__ int s_cnt[NN * NN];   // 16 KB
    __shared__ int s_deg[NN];
    __shared__ float s_dinv[NN];
    const int t = threadIdx.x;
    for (int i = t; i < NN * NN; i += 320) s_cnt[i] = 0;
    if (t < NN) s_deg[t] = 0;
    __syncthreads();
    int src, dst;
    if (t < EE) { src = ei[t]; dst = ei[EE + t]; }
    else        { src = t - EE; dst = t - EE; }
    atomicAdd(&s_deg[dst], 1);                 // integer: order-independent, deterministic
    atomicAdd(&s_cnt[dst * NN + src], 1);
    __syncthreads();
    if (t < NN) s_dinv[t] = rsqrtf((float)s_deg[t]);   // deg >= 1 (self loop)
    __syncthreads();
    for (int i = t; i < NN * NN; i += 320) {
        const int n = i >> 6, m = i & 63;
        Ahat[i] = __float2bfloat16((float)s_cnt[i] * s_dinv[m] * s_dinv[n]);
    }
}

// ---------------- kernel 2: Wt[o][c] = W[c][o] (bf16) ----------------
__global__ __launch_bounds__(256) void k_wt(const float* __restrict__ W,
                                            __hip_bfloat16* __restrict__ Wt) {
    const int idx = blockIdx.x * 256 + threadIdx.x;   // 32768
    const int o = idx >> 7, c = idx & 127;
    Wt[idx] = __float2bfloat16(W[c * CO + o]);
}

// ---------------- kernel 3: w_conv [o][i][k] -> W2t[o][q], q = kk*256 + i ----------------
__global__ __launch_bounds__(256) void k_w2t(const float* __restrict__ wconv,
                                             __hip_bfloat16* __restrict__ W2t) {
    const int idx = blockIdx.x * 256 + threadIdx.x;   // o*768 + q
    const int o = idx / 768, q = idx - o * 768;
    const int kk = q >> 8, i = q & 255;
    W2t[idx] = __float2bfloat16(wconv[(o * CO + i) * KWIN + kk]);
}

// ---------------- kernel 4: fused GCN via MFMA: xgcn[b] = Ahat @ x[b] @ W + bgcn ----------------
// G1: tmp[n][c] = sum_m Ahat[n][m] x[b][m][c]   (M=64,N=128,K=64)
// G2: out[n][o] = sum_c tmp[n][c] Wt[o][c]      (M=64,N=256,K=128), B-frags from global (L2)
__global__ __launch_bounds__(256) void k_gcn(const float* __restrict__ x,
                                             const __hip_bfloat16* __restrict__ Ahat_,
                                             const __hip_bfloat16* __restrict__ Wt_,
                                             const float* __restrict__ bgcn,
                                             __hip_bfloat16* __restrict__ xgcn_) {
    __shared__ __align__(16) char smem[40960];
    unsigned short* sxT  = (unsigned short*)smem;            // [128 c][64 m]  swizzled
    unsigned short* sAh  = (unsigned short*)(smem + 16384);  // [64 n][64 m]   swizzled
    unsigned short* stm  = (unsigned short*)(smem + 24576);  // [64 n][128 c]  swizzled
    unsigned short* sout = (unsigned short*)smem;            // [64 n][256 o]  (reuse)
    const unsigned short* Ahat = (const unsigned short*)Ahat_;
    const unsigned short* Wt   = (const unsigned short*)Wt_;
    unsigned short* xgcn = (unsigned short*)xgcn_;

    const int b = blockIdx.x, tid = threadIdx.x;
    const int lane = tid & 63, wid = tid >> 6;
    const int llo = lane & 15, lhi = lane >> 4;

    // ---- stage x[b] (f32 -> bf16, transposed to [c][m], XOR-swizzled) ----
    const float4* xb4 = (const float4*)(x + (size_t)b * NN * CIN);
#pragma unroll
    for (int i = 0; i < 8; ++i) {
        const int f = tid + 256 * i;
        const int m = f >> 5, c0 = (f & 31) * 4;
        const float4 v = xb4[f];
        const float vv[4] = {v.x, v.y, v.z, v.w};
#pragma unroll
        for (int j = 0; j < 4; ++j) {
            const int c = c0 + j;
            sxT[c * 64 + (m ^ ((c & 7) << 3))] = f2bfu(vv[j]);
        }
    }
    // ---- stage Ahat [n][m] swizzled ----
    {
        const int n = tid >> 2, mb = (tid & 3) * 16;
        const int sw = (n & 7) << 3;
        const us8 a0 = *(const us8*)(Ahat + n * 64 + mb);
        const us8 a1 = *(const us8*)(Ahat + n * 64 + mb + 8);
        *(us8*)&sAh[n * 64 + (mb ^ sw)] = a0;
        *(us8*)&sAh[n * 64 + ((mb + 8) ^ sw)] = a1;
    }
    __syncthreads();

    // ---- G1: tmp = Ahat @ x[b]; wave w owns cols w*32..+32 ----
    f32x4 acc1[4][2];
#pragma unroll
    for (int p = 0; p < 4; ++p)
#pragma unroll
        for (int q = 0; q < 2; ++q) acc1[p][q] = (f32x4){0.f, 0.f, 0.f, 0.f};
#pragma unroll
    for (int s = 0; s < 2; ++s) {
        const int k0 = s * 32 + lhi * 8;
        short8 af[4], bf[2];
#pragma unroll
        for (int p = 0; p < 4; ++p) {
            const int n = p * 16 + llo;
            af[p] = *(const short8*)&sAh[n * 64 + (k0 ^ ((n & 7) << 3))];
        }
#pragma unroll
        for (int q = 0; q < 2; ++q) {
            const int c = wid * 32 + q * 16 + llo;
            bf[q] = *(const short8*)&sxT[c * 64 + (k0 ^ ((c & 7) << 3))];
        }
#pragma unroll
        for (int p = 0; p < 4; ++p)
#pragma unroll
            for (int q = 0; q < 2; ++q)
                acc1[p][q] = __builtin_amdgcn_mfma_f32_16x16x32_bf16(af[p], bf[q], acc1[p][q], 0, 0, 0);
    }
    // tmp -> LDS [n][128 c] bf16 swizzled. C/D layout: col=llo, row=lhi*4+reg
#pragma unroll
    for (int p = 0; p < 4; ++p)
#pragma unroll
        for (int q = 0; q < 2; ++q)
#pragma unroll
            for (int reg = 0; reg < 4; ++reg) {
                const int n = p * 16 + lhi * 4 + reg;
                const int c = wid * 32 + q * 16 + llo;
                stm[n * 128 + (c ^ ((n & 7) << 3))] = f2bfu(acc1[p][q][reg]);
            }
    __syncthreads();

    // ---- G2: out = tmp @ W; wave w owns o-cols w*64..+64; B-frags from global Wt (L2-hot) ----
    f32x4 acc2[4][4];
#pragma unroll
    for (int p = 0; p < 4; ++p)
#pragma unroll
        for (int q = 0; q < 4; ++q) acc2[p][q] = (f32x4){0.f, 0.f, 0.f, 0.f};
#pragma unroll
    for (int s = 0; s < 4; ++s) {
        const int k0 = s * 32 + lhi * 8;
        short8 af[4], bf[4];
#pragma unroll
        for (int p = 0; p < 4; ++p) {
            const int n = p * 16 + llo;
            af[p] = *(const short8*)&stm[n * 128 + (k0 ^ ((n & 7) << 3))];
        }
#pragma unroll
        for (int q = 0; q < 4; ++q) {
            const int o = wid * 64 + q * 16 + llo;
            bf[q] = *(const short8*)&Wt[o * 128 + k0];
        }
#pragma unroll
        for (int p = 0; p < 4; ++p)
#pragma unroll
            for (int q = 0; q < 4; ++q)
                acc2[p][q] = __builtin_amdgcn_mfma_f32_16x16x32_bf16(af[p], bf[q], acc2[p][q], 0, 0, 0);
    }
    __syncthreads();   // all stm/sxT reads done before sout overwrites the region

    // ---- epilogue: +bgcn, bf16, coalesced store via LDS ----
    float bg[4];
#pragma unroll
    for (int q = 0; q < 4; ++q) bg[q] = bgcn[wid * 64 + q * 16 + llo];
#pragma unroll
    for (int p = 0; p < 4; ++p)
#pragma unroll
        for (int q = 0; q < 4; ++q)
#pragma unroll
            for (int reg = 0; reg < 4; ++reg) {
                const int n = p * 16 + lhi * 4 + reg;
                const int o = wid * 64 + q * 16 + llo;
                sout[n * 256 + o] = f2bfu(acc2[p][q][reg] + bg[q]);
            }
    __syncthreads();
    unsigned short* dst = xgcn + (size_t)b * NN * CO;
#pragma unroll
    for (int i = 0; i < 8; ++i) {
        const int f = tid + 256 * i;
        *(us8*)(dst + f * 8) = *(const us8*)&sout[f * 8];
    }
}

// ---------------- kernel 5: conv1d-as-GEMM, bf16 MFMA + bias + BN partials ----------------
__global__ __launch_bounds__(256) void k_conv(const __hip_bfloat16* __restrict__ xgcn_,
                                              const __hip_bfloat16* __restrict__ W2t_,
                                              const float* __restrict__ bconv,
                                              float* __restrict__ y,
                                              float* __restrict__ partials) {
    __shared__ unsigned short sA[128 * 64];   // 16 KB, [row t][64 k], XOR-swizzled
    __shared__ unsigned short sB[128 * 64];   // 16 KB, [row o][64 k], XOR-swizzled
    const unsigned short* xgcn = (const unsigned short*)xgcn_;
    const unsigned short* W2t  = (const unsigned short*)W2t_;

    const int tt = blockIdx.x, ot = blockIdx.y, n = blockIdx.z;
    const int tid = threadIdx.x;
    const int lane = tid & 63, wid = tid >> 6;
    const int t0 = tt * 128, o0 = ot * 128;
    const int wm0 = (wid >> 1) * 64, wn0 = (wid & 1) * 64;
    const int lhi = lane >> 4, llo = lane & 15;

    f32x4 acc[4][4];
#pragma unroll
    for (int m = 0; m < 4; ++m)
#pragma unroll
        for (int nn = 0; nn < 4; ++nn) acc[m][nn] = (f32x4){0.f, 0.f, 0.f, 0.f};

    const int srsub = lane >> 3;
    const int scol  = (((lane & 7) ^ srsub) << 3);   // inverse-swizzled source col

    for (int kc = 0; kc < 12; ++kc) {
        const int kk = kc >> 2;
        const int i0 = (kc & 3) * 64;
        const int q0 = kc * 64;
#pragma unroll
        for (int iss = 0; iss < 4; ++iss) {
            const int row = wid * 32 + iss * 8 + srsub;
            int tg = t0 + row + kk - 1;
            tg = min(max(tg, 0), BB - 1);
            gload_lds16(xgcn + ((size_t)tg * NN + n) * CO + i0 + scol,
                        sA + (wid * 32 + iss * 8) * 64);
        }
#pragma unroll
        for (int iss = 0; iss < 4; ++iss) {
            const int row = wid * 32 + iss * 8 + srsub;
            gload_lds16(W2t + (size_t)(o0 + row) * (CO * KWIN) + q0 + scol,
                        sB + (wid * 32 + iss * 8) * 64);
        }
        __syncthreads();
        if ((tt == 0 && kc < 4) || (tt == 15 && kc >= 8)) {   // halo rows -> zero
            const int zr = (tt == 0) ? 0 : 127;
            if (tid < 8) *(uint4*)&sA[zr * 64 + tid * 8] = make_uint4(0u, 0u, 0u, 0u);
            __syncthreads();
        }
#pragma unroll
        for (int s = 0; s < 2; ++s) {
            const int cu = s * 32 + lhi * 8;
            short8 af[4], bf[4];
#pragma unroll
            for (int m = 0; m < 4; ++m) {
                const int row = wm0 + m * 16 + llo;
                af[m] = *(const short8*)&sA[row * 64 + (cu ^ ((row & 7) << 3))];
            }
#pragma unroll
            for (int nn = 0; nn < 4; ++nn) {
                const int row = wn0 + nn * 16 + llo;
                bf[nn] = *(const short8*)&sB[row * 64 + (cu ^ ((row & 7) << 3))];
            }
#pragma unroll
            for (int m = 0; m < 4; ++m)
#pragma unroll
                for (int nn = 0; nn < 4; ++nn)
                    acc[m][nn] = __builtin_amdgcn_mfma_f32_16x16x32_bf16(af[m], bf[nn], acc[m][nn], 0, 0, 0);
        }
        __syncthreads();
    }

    float bc[4], s1v[4], s2v[4];
#pragma unroll
    for (int nn = 0; nn < 4; ++nn) {
        bc[nn] = bconv[o0 + wn0 + nn * 16 + llo];
        s1v[nn] = 0.f; s2v[nn] = 0.f;
    }
#pragma unroll
    for (int m = 0; m < 4; ++m) {
#pragma unroll
        for (int reg = 0; reg < 4; ++reg) {
            const int trow = t0 + wm0 + m * 16 + lhi * 4 + reg;
            float* dst = y + ((size_t)trow * NN + n) * CO + o0 + wn0 + llo;
#pragma unroll
            for (int nn = 0; nn < 4; ++nn) {
                const float v = acc[m][nn][reg] + bc[nn];
                dst[nn * 16] = v;
                s1v[nn] += v;
                s2v[nn] += v * v;
            }
        }
    }
    float* sred1 = (float*)sA;          // [8][128]
    float* sred2 = sred1 + 1024;
    const int rg = (wid >> 1) * 4 + lhi;
#pragma unroll
    for (int nn = 0; nn < 4; ++nn) {
        const int cl = wn0 + nn * 16 + llo;
        sred1[rg * 128 + cl] = s1v[nn];
        sred2[rg * 128 + cl] = s2v[nn];
    }
    __syncthreads();
    if (tid < 128) {
        float a = 0.f, b2 = 0.f;
#pragma unroll
        for (int r = 0; r < 8; ++r) { a += sred1[r * 128 + tid]; b2 += sred2[r * 128 + tid]; }
        float* pb = partials + (size_t)((n * 2 + ot) * 16 + tt) * 256;
        pb[tid * 2]     = a;
        pb[tid * 2 + 1] = b2;
    }
}

// ---------------- kernel 6: reduce BN partials -> scale/shift per channel ----------------
__global__ __launch_bounds__(256) void k_bnstats(const float* __restrict__ partials,
                                                 const float* __restrict__ gamma,
                                                 const float* __restrict__ beta,
                                                 float* __restrict__ scl,
                                                 float* __restrict__ shf) {
    const int o = blockIdx.x, tid = threadIdx.x;
    const int ot = o >> 7, c = o & 127;
    float s1 = 0.f, s2 = 0.f;
    for (int i = tid; i < 1024; i += 256) {
        const int nn = i >> 4, tt = i & 15;
        const float* p = partials + ((size_t)((nn * 2 + ot) * 16 + tt)) * 256 + c * 2;
        s1 += p[0]; s2 += p[1];
    }
    __shared__ float r1[256], r2[256];
    r1[tid] = s1; r2[tid] = s2;
    __syncthreads();
    for (int s = 128; s > 0; s >>= 1) {
        if (tid < s) { r1[tid] += r1[tid + s]; r2[tid] += r2[tid + s]; }
        __syncthreads();
    }
    if (tid == 0) {
        const float inv = 1.f / (float)((size_t)BB * NN);
        const float mean = r1[0] * inv;
        const float var  = r2[0] * inv - mean * mean;
        const float sc = gamma[o] * rsqrtf(var + EPSBN);
        scl[o] = sc;
        shf[o] = beta[o] - mean * sc;
    }
}

// ---------------- kernel 7: in-place BN apply + ReLU ----------------
__global__ __launch_bounds__(256) void k_apply(float* __restrict__ y,
                                               const float* __restrict__ scl,
                                               const float* __restrict__ shf) {
    __shared__ float ssc[CO], ssh[CO];
    const int tid = threadIdx.x;
    ssc[tid] = scl[tid]; ssh[tid] = shf[tid];
    __syncthreads();
    const size_t total4 = (size_t)BB * NN * CO / 4;
    float4* y4 = (float4*)y;
    for (size_t i = (size_t)blockIdx.x * 256 + tid; i < total4; i += (size_t)gridDim.x * 256) {
        float4 v = y4[i];
        const int ob = (int)((i * 4) & (CO - 1));
        v.x = fmaxf(0.f, v.x * ssc[ob]     + ssh[ob]);
        v.y = fmaxf(0.f, v.y * ssc[ob + 1] + ssh[ob + 1]);
        v.z = fmaxf(0.f, v.z * ssc[ob + 2] + ssh[ob + 2]);
        v.w = fmaxf(0.f, v.w * ssc[ob + 3] + ssh[ob + 3]);
        y4[i] = v;
    }
}

extern "C" void kernel_launch(void* const* d_in, const int* in_sizes, int n_in,
                              void* d_out, int out_size, void* d_ws, size_t ws_size,
                              hipStream_t stream) {
    const float* x     = (const float*)d_in[0];
    const float* W     = (const float*)d_in[1];
    const float* bgcn  = (const float*)d_in[2];
    const float* wconv = (const float*)d_in[3];
    const float* bconv = (const float*)d_in[4];
    const float* gamma = (const float*)d_in[5];
    const float* beta  = (const float*)d_in[6];
    const int*   ei    = (const int*)d_in[7];
    float* out = (float*)d_out;

    char* ws = (char*)d_ws;
    size_t off = 0;
    __hip_bfloat16* xgcn = (__hip_bfloat16*)(ws + off); off += (size_t)BB * NN * CO * 2;   // 67 MiB
    __hip_bfloat16* W2t  = (__hip_bfloat16*)(ws + off); off += (size_t)CO * KWIN * CO * 2; // 384 KiB
    __hip_bfloat16* Ahat = (__hip_bfloat16*)(ws + off); off += (size_t)NN * NN * 2;        // 8 KiB
    __hip_bfloat16* Wt   = (__hip_bfloat16*)(ws + off); off += (size_t)CO * CIN * 2;       // 64 KiB
    float* partials = (float*)(ws + off); off += (size_t)2048 * 256 * 4;                   // 2 MiB
    float* scl = (float*)(ws + off); off += 256 * 4;
    float* shf = (float*)(ws + off); off += 256 * 4;

    k_setup<<<1, 320, 0, stream>>>(ei, Ahat);
    k_wt<<<128, 256, 0, stream>>>(W, Wt);
    k_w2t<<<768, 256, 0, stream>>>(wconv, W2t);
    k_gcn<<<BB, 256, 0, stream>>>(x, Ahat, Wt, bgcn, xgcn);
    k_conv<<<dim3(16, 2, 64), 256, 0, stream>>>(xgcn, W2t, bconv, out, partials);
    k_bnstats<<<256, 256, 0, stream>>>(partials, gamma, beta, scl, shf);
    k_apply<<<2048, 256, 0, stream>>>(out, scl, shf);
}

// Round 4
// 156.243 us; speedup vs baseline: 7.1620x; 1.0719x over previous
//
#include <hip/hip_runtime.h>
#include <hip/hip_bf16.h>

typedef __attribute__((ext_vector_type(8))) unsigned short us8;
typedef __attribute__((ext_vector_type(4))) unsigned short us4;
typedef __attribute__((ext_vector_type(8))) short short8;
typedef __attribute__((ext_vector_type(4))) float f32x4;

#define BB 2048
#define NN 64
#define CIN 128
#define CO 256
#define KWIN 3
#define EE 256
#define NE 320            // E + N (self loops)
#define EPSBN 1e-5f

static __device__ __forceinline__ void gload_lds16(const unsigned short* g, unsigned short* l) {
    __builtin_amdgcn_global_load_lds(
        (const __attribute__((address_space(1))) unsigned int*)g,
        (__attribute__((address_space(3))) unsigned int*)l,
        16, 0, 0);
}

static __device__ __forceinline__ float bf2f(unsigned short u) {
    return __uint_as_float(((unsigned int)u) << 16);
}

static __device__ __forceinline__ unsigned short f2bfu(float f) {
    unsigned int u = __float_as_uint(f);
    u = (u + 0x7FFFu + ((u >> 16) & 1u)) >> 16;   // RN-even
    return (unsigned short)u;
}

// ---------------- kernel 1: dense normalized adjacency Ahat[dst][src] (bf16), deterministic ----------------
__global__ __launch_bounds__(320) void k_setup(const int* __restrict__ ei,
                                               __hip_bfloat16* __restrict__ Ahat) {
    __shared__ int s_cnt[NN * NN];   // 16 KB
    __shared__ int s_deg[NN];
    __shared__ float s_dinv[NN];
    const int t = threadIdx.x;
    for (int i = t; i < NN * NN; i += 320) s_cnt[i] = 0;
    if (t < NN) s_deg[t] = 0;
    __syncthreads();
    int src, dst;
    if (t < EE) { src = ei[t]; dst = ei[EE + t]; }
    else        { src = t - EE; dst = t - EE; }
    atomicAdd(&s_deg[dst], 1);                 // integer: order-independent, deterministic
    atomicAdd(&s_cnt[dst * NN + src], 1);
    __syncthreads();
    if (t < NN) s_dinv[t] = rsqrtf((float)s_deg[t]);   // deg >= 1 (self loop)
    __syncthreads();
    for (int i = t; i < NN * NN; i += 320) {
        const int n = i >> 6, m = i & 63;
        Ahat[i] = __float2bfloat16((float)s_cnt[i] * s_dinv[m] * s_dinv[n]);
    }
}

// ---------------- kernel 2: pack weights: Wt[o][c]=W[c][o]; W2t[o][kk*256+i]=wconv[o][i][kk] ----------------
__global__ __launch_bounds__(256) void k_weights(const float* __restrict__ W,
                                                 const float* __restrict__ wconv,
                                                 __hip_bfloat16* __restrict__ Wt,
                                                 __hip_bfloat16* __restrict__ W2t) {
    const int idx = blockIdx.x * 256 + threadIdx.x;
    if (idx < CO * CIN) {                                 // 32768
        const int o = idx >> 7, c = idx & 127;
        Wt[idx] = __float2bfloat16(W[c * CO + o]);
    }
    const int j = idx - CO * CIN;
    if (j >= 0 && j < CO * KWIN * CO) {                   // 196608
        const int o = j / 768, q = j - o * 768;
        const int kk = q >> 8, i = q & 255;
        W2t[j] = __float2bfloat16(wconv[(o * CO + i) * KWIN + kk]);
    }
}

// ---------------- kernel 3: fused GCN via MFMA: xgcn[b] = Ahat @ (x[b] @ W) + bgcn ----------------
// G1: tmp2[m][o] = sum_c x[b][m][c] Wt[o][c]   (M=64,N=256,K=128); A from LDS sx, B from global Wt (L2)
// G2: out[n][o]  = sum_m Ahat[n][m] tmp2[m][o] (M=64,N=256,K=64);  A from global Ahat (L1), B from LDS stm
__global__ __launch_bounds__(256) void k_gcn(const float* __restrict__ x,
                                             const __hip_bfloat16* __restrict__ Ahat_,
                                             const __hip_bfloat16* __restrict__ Wt_,
                                             const float* __restrict__ bgcn,
                                             __hip_bfloat16* __restrict__ xgcn_) {
    __shared__ __align__(16) unsigned short sx[64 * 128];    // [m][c] swizzled, 16 KB
    __shared__ __align__(16) unsigned short stm[256 * 64];   // [o][m] swizzled, 32 KB (wave-private rows)
    const unsigned short* Ahat = (const unsigned short*)Ahat_;
    const unsigned short* Wt   = (const unsigned short*)Wt_;
    unsigned short* xgcn = (unsigned short*)xgcn_;

    const int b = blockIdx.x, tid = threadIdx.x;
    const int lane = tid & 63, wid = tid >> 6;
    const int llo = lane & 15, lhi = lane >> 4;

    // ---- stage x[b] f32 -> sx bf16 [m][c], XOR-swizzled cols, row-contiguous writes ----
#pragma unroll
    for (int r = 0; r < 4; ++r) {
        const int f = tid + 256 * r;
        const int m = f >> 4, c0 = (f & 15) * 8;
        const float4* src = (const float4*)(x + ((size_t)b * NN + m) * CIN + c0);
        const float4 v0 = src[0], v1 = src[1];
        unsigned short t8[8] = {f2bfu(v0.x), f2bfu(v0.y), f2bfu(v0.z), f2bfu(v0.w),
                                f2bfu(v1.x), f2bfu(v1.y), f2bfu(v1.z), f2bfu(v1.w)};
        *(us8*)&sx[m * 128 + (c0 ^ ((m & 7) << 3))] = *(const us8*)t8;
    }
    __syncthreads();

    // ---- G1: tmp2 = x[b] @ W; wave owns o-cols wid*64..+64 ----
    f32x4 acc1[4][4];
#pragma unroll
    for (int p = 0; p < 4; ++p)
#pragma unroll
        for (int q = 0; q < 4; ++q) acc1[p][q] = (f32x4){0.f, 0.f, 0.f, 0.f};
#pragma unroll
    for (int s = 0; s < 4; ++s) {
        const int k0 = s * 32 + lhi * 8;
        short8 af[4], bf[4];
#pragma unroll
        for (int p = 0; p < 4; ++p) {
            const int m = p * 16 + llo;
            af[p] = *(const short8*)&sx[m * 128 + (k0 ^ ((m & 7) << 3))];
        }
#pragma unroll
        for (int q = 0; q < 4; ++q) {
            const int o = wid * 64 + q * 16 + llo;
            bf[q] = *(const short8*)&Wt[o * 128 + k0];   // global, L2-hot
        }
#pragma unroll
        for (int p = 0; p < 4; ++p)
#pragma unroll
            for (int q = 0; q < 4; ++q)
                acc1[p][q] = __builtin_amdgcn_mfma_f32_16x16x32_bf16(af[p], bf[q], acc1[p][q], 0, 0, 0);
    }
    // tmp2 -> stm [o][m] swizzled; wave-private rows -> NO barrier needed (same-wave RAW via lgkmcnt)
#pragma unroll
    for (int p = 0; p < 4; ++p)
#pragma unroll
        for (int q = 0; q < 4; ++q) {
            const int o = wid * 64 + q * 16 + llo;
            const int bm = p * 16 + lhi * 4;
            unsigned short t4[4] = {f2bfu(acc1[p][q][0]), f2bfu(acc1[p][q][1]),
                                    f2bfu(acc1[p][q][2]), f2bfu(acc1[p][q][3])};
            *(us4*)&stm[o * 64 + (bm ^ ((o & 7) << 3))] = *(const us4*)t4;
        }

    // ---- G2: out = Ahat @ tmp2; A-frags from global Ahat (8 KB, L1-hot) ----
    f32x4 acc2[4][4];
#pragma unroll
    for (int p = 0; p < 4; ++p)
#pragma unroll
        for (int q = 0; q < 4; ++q) acc2[p][q] = (f32x4){0.f, 0.f, 0.f, 0.f};
#pragma unroll
    for (int s = 0; s < 2; ++s) {
        const int k0 = s * 32 + lhi * 8;
        short8 af[4], bf[4];
#pragma unroll
        for (int p = 0; p < 4; ++p) {
            const int n = p * 16 + llo;
            af[p] = *(const short8*)&Ahat[n * 64 + k0];
        }
#pragma unroll
        for (int q = 0; q < 4; ++q) {
            const int o = wid * 64 + q * 16 + llo;
            bf[q] = *(const short8*)&stm[o * 64 + (k0 ^ ((o & 7) << 3))];
        }
#pragma unroll
        for (int p = 0; p < 4; ++p)
#pragma unroll
            for (int q = 0; q < 4; ++q)
                acc2[p][q] = __builtin_amdgcn_mfma_f32_16x16x32_bf16(af[p], bf[q], acc2[p][q], 0, 0, 0);
    }

    // ---- epilogue: +bgcn, direct bf16 scatter (L2 write-merges; full coverage) ----
    float bg[4];
#pragma unroll
    for (int q = 0; q < 4; ++q) bg[q] = bgcn[wid * 64 + q * 16 + llo];
    unsigned short* dst = xgcn + (size_t)b * NN * CO;
#pragma unroll
    for (int p = 0; p < 4; ++p)
#pragma unroll
        for (int q = 0; q < 4; ++q) {
            const int o = wid * 64 + q * 16 + llo;
#pragma unroll
            for (int reg = 0; reg < 4; ++reg) {
                const int n = p * 16 + lhi * 4 + reg;
                dst[n * CO + o] = f2bfu(acc2[p][q][reg] + bg[q]);
            }
        }
}

// ---------------- kernel 4: conv1d-as-GEMM, A-slab reuse + B double-buffer prefetch, y bf16 ----------------
__global__ __launch_bounds__(256) void k_conv(const __hip_bfloat16* __restrict__ xgcn_,
                                              const __hip_bfloat16* __restrict__ W2t_,
                                              const float* __restrict__ bconv,
                                              __hip_bfloat16* __restrict__ y_,
                                              float* __restrict__ partials) {
    __shared__ __align__(16) unsigned short sA[136 * 64];      // A slab: rows t0-1..t0+134, 17 KB
    __shared__ __align__(16) unsigned short sB[2][128 * 64];   // B dbuf: 2 x 16 KB
    const unsigned short* xgcn = (const unsigned short*)xgcn_;
    const unsigned short* W2t  = (const unsigned short*)W2t_;
    unsigned short* y = (unsigned short*)y_;

    const int tt = blockIdx.x, ot = blockIdx.y, n = blockIdx.z;
    const int tid = threadIdx.x;
    const int lane = tid & 63, wid = tid >> 6;
    const int t0 = tt * 128, o0 = ot * 128;
    const int wm0 = (wid >> 1) * 64, wn0 = (wid & 1) * 64;
    const int lhi = lane >> 4, llo = lane & 15;

    f32x4 acc[4][4];
#pragma unroll
    for (int m = 0; m < 4; ++m)
#pragma unroll
        for (int nn = 0; nn < 4; ++nn) acc[m][nn] = (f32x4){0.f, 0.f, 0.f, 0.f};

    const int srsub = lane >> 3;
    const int scol  = (((lane & 7) ^ srsub) << 3);   // inverse-swizzled source col

    for (int g = 0; g < 4; ++g) {
        const int i0 = g * 64;
        // ---- stage A slab (17 issues round-robin over waves); slab row r <-> t = t0-1+r ----
        for (int iss = wid; iss < 17; iss += 4) {
            const int rbase = iss * 8;
            int tg = t0 - 1 + rbase + srsub;
            tg = min(max(tg, 0), BB - 1);             // clamped; halo rows zeroed below
            gload_lds16(xgcn + ((size_t)tg * NN + n) * CO + i0 + scol, sA + rbase * 64);
        }
        // ---- stage B chunk kk=0 into buf 0 ----
#pragma unroll
        for (int iss = 0; iss < 4; ++iss) {
            const int rbase = wid * 32 + iss * 8;
            gload_lds16(W2t + (size_t)(o0 + rbase + srsub) * (CO * KWIN) + i0 + scol,
                        sB[0] + rbase * 64);
        }
        __syncthreads();   // drains vmcnt(0)
        if (tt == 0 || tt == 15) {                    // halo row zero (block-uniform branch)
            const int zr = (tt == 0) ? 0 : 129;
            if (tid < 8) *(uint4*)&sA[zr * 64 + tid * 8] = make_uint4(0u, 0u, 0u, 0u);
            __syncthreads();
        }
#pragma unroll
        for (int kk = 0; kk < 3; ++kk) {
            if (kk < 2) {                              // prefetch next B chunk into other buf
                const int q0 = (kk + 1) * 256 + i0;
#pragma unroll
                for (int iss = 0; iss < 4; ++iss) {
                    const int rbase = wid * 32 + iss * 8;
                    gload_lds16(W2t + (size_t)(o0 + rbase + srsub) * (CO * KWIN) + q0 + scol,
                                sB[(kk + 1) & 1] + rbase * 64);
                }
            }
#pragma unroll
            for (int s = 0; s < 2; ++s) {
                const int cu = s * 32 + lhi * 8;
                short8 af[4], bf[4];
#pragma unroll
                for (int m = 0; m < 4; ++m) {
                    const int sr = wm0 + m * 16 + llo + kk;     // slab row (t + kk - 1 shift)
                    af[m] = *(const short8*)&sA[sr * 64 + (cu ^ ((sr & 7) << 3))];
                }
#pragma unroll
                for (int nn = 0; nn < 4; ++nn) {
                    const int row = wn0 + nn * 16 + llo;
                    bf[nn] = *(const short8*)&sB[kk & 1][row * 64 + (cu ^ ((row & 7) << 3))];
                }
#pragma unroll
                for (int m = 0; m < 4; ++m)
#pragma unroll
                    for (int nn = 0; nn < 4; ++nn)
                        acc[m][nn] = __builtin_amdgcn_mfma_f32_16x16x32_bf16(af[m], bf[nn], acc[m][nn], 0, 0, 0);
            }
            __syncthreads();   // prefetched B landed (vmcnt0) + all reads of cur buf done
        }
    }

    // ---- epilogue: +bias, store y bf16, per-block BN partials (f32-exact) ----
    float bc[4], s1v[4], s2v[4];
#pragma unroll
    for (int nn = 0; nn < 4; ++nn) {
        bc[nn] = bconv[o0 + wn0 + nn * 16 + llo];
        s1v[nn] = 0.f; s2v[nn] = 0.f;
    }
#pragma unroll
    for (int m = 0; m < 4; ++m) {
#pragma unroll
        for (int reg = 0; reg < 4; ++reg) {
            const int trow = t0 + wm0 + m * 16 + lhi * 4 + reg;
            unsigned short* dst = y + ((size_t)trow * NN + n) * CO + o0 + wn0 + llo;
#pragma unroll
            for (int nn = 0; nn < 4; ++nn) {
                const float v = acc[m][nn][reg] + bc[nn];
                dst[nn * 16] = f2bfu(v);
                s1v[nn] += v;
                s2v[nn] += v * v;
            }
        }
    }
    float* sred1 = (float*)sA;          // [8][128] (reuse; 8 KB of 17 KB)
    float* sred2 = sred1 + 1024;
    const int rg = (wid >> 1) * 4 + lhi;
#pragma unroll
    for (int nn = 0; nn < 4; ++nn) {
        const int cl = wn0 + nn * 16 + llo;
        sred1[rg * 128 + cl] = s1v[nn];
        sred2[rg * 128 + cl] = s2v[nn];
    }
    __syncthreads();
    if (tid < 128) {
        float a = 0.f, b2 = 0.f;
#pragma unroll
        for (int r = 0; r < 8; ++r) { a += sred1[r * 128 + tid]; b2 += sred2[r * 128 + tid]; }
        float* pb = partials + (size_t)((n * 2 + ot) * 16 + tt) * 256;
        pb[tid * 2]     = a;
        pb[tid * 2 + 1] = b2;
    }
}

// ---------------- kernel 5: reduce BN partials -> scale/shift per channel ----------------
__global__ __launch_bounds__(256) void k_bnstats(const float* __restrict__ partials,
                                                 const float* __restrict__ gamma,
                                                 const float* __restrict__ beta,
                                                 float* __restrict__ scl,
                                                 float* __restrict__ shf) {
    const int o = blockIdx.x, tid = threadIdx.x;
    const int ot = o >> 7, c = o & 127;
    float s1 = 0.f, s2 = 0.f;
    for (int i = tid; i < 1024; i += 256) {
        const int nn = i >> 4, tt = i & 15;
        const float* p = partials + ((size_t)((nn * 2 + ot) * 16 + tt)) * 256 + c * 2;
        s1 += p[0]; s2 += p[1];
    }
    __shared__ float r1[256], r2[256];
    r1[tid] = s1; r2[tid] = s2;
    __syncthreads();
    for (int s = 128; s > 0; s >>= 1) {
        if (tid < s) { r1[tid] += r1[tid + s]; r2[tid] += r2[tid + s]; }
        __syncthreads();
    }
    if (tid == 0) {
        const float inv = 1.f / (float)((size_t)BB * NN);
        const float mean = r1[0] * inv;
        const float var  = r2[0] * inv - mean * mean;
        const float sc = gamma[o] * rsqrtf(var + EPSBN);
        scl[o] = sc;
        shf[o] = beta[o] - mean * sc;
    }
}

// ---------------- kernel 6: BN apply + ReLU: y bf16 -> out f32 ----------------
__global__ __launch_bounds__(256) void k_apply(const unsigned short* __restrict__ y,
                                               float* __restrict__ out,
                                               const float* __restrict__ scl,
                                               const float* __restrict__ shf) {
    __shared__ float ssc[CO], ssh[CO];
    const int tid = threadIdx.x;
    ssc[tid] = scl[tid]; ssh[tid] = shf[tid];
    __syncthreads();
    const size_t total8 = (size_t)BB * NN * CO / 8;
    float4* out4 = (float4*)out;
    for (size_t i = (size_t)blockIdx.x * 256 + tid; i < total8; i += (size_t)gridDim.x * 256) {
        const us8 v = *(const us8*)(y + i * 8);
        const int ob = (int)((i * 8) & (CO - 1));
        float4 r0, r1;
        r0.x = fmaxf(0.f, bf2f(v[0]) * ssc[ob + 0] + ssh[ob + 0]);
        r0.y = fmaxf(0.f, bf2f(v[1]) * ssc[ob + 1] + ssh[ob + 1]);
        r0.z = fmaxf(0.f, bf2f(v[2]) * ssc[ob + 2] + ssh[ob + 2]);
        r0.w = fmaxf(0.f, bf2f(v[3]) * ssc[ob + 3] + ssh[ob + 3]);
        r1.x = fmaxf(0.f, bf2f(v[4]) * ssc[ob + 4] + ssh[ob + 4]);
        r1.y = fmaxf(0.f, bf2f(v[5]) * ssc[ob + 5] + ssh[ob + 5]);
        r1.z = fmaxf(0.f, bf2f(v[6]) * ssc[ob + 6] + ssh[ob + 6]);
        r1.w = fmaxf(0.f, bf2f(v[7]) * ssc[ob + 7] + ssh[ob + 7]);
        out4[i * 2]     = r0;
        out4[i * 2 + 1] = r1;
    }
}

extern "C" void kernel_launch(void* const* d_in, const int* in_sizes, int n_in,
                              void* d_out, int out_size, void* d_ws, size_t ws_size,
                              hipStream_t stream) {
    const float* x     = (const float*)d_in[0];
    const float* W     = (const float*)d_in[1];
    const float* bgcn  = (const float*)d_in[2];
    const float* wconv = (const float*)d_in[3];
    const float* bconv = (const float*)d_in[4];
    const float* gamma = (const float*)d_in[5];
    const float* beta  = (const float*)d_in[6];
    const int*   ei    = (const int*)d_in[7];
    float* out = (float*)d_out;

    char* ws = (char*)d_ws;
    size_t off = 0;
    __hip_bfloat16* xgcn = (__hip_bfloat16*)(ws + off); off += (size_t)BB * NN * CO * 2;   // 67 MB
    __hip_bfloat16* ybuf = (__hip_bfloat16*)(ws + off); off += (size_t)BB * NN * CO * 2;   // 67 MB
    __hip_bfloat16* W2t  = (__hip_bfloat16*)(ws + off); off += (size_t)CO * KWIN * CO * 2; // 384 KB
    __hip_bfloat16* Ahat = (__hip_bfloat16*)(ws + off); off += (size_t)NN * NN * 2;        // 8 KB
    __hip_bfloat16* Wt   = (__hip_bfloat16*)(ws + off); off += (size_t)CO * CIN * 2;       // 64 KB
    float* partials = (float*)(ws + off); off += (size_t)2048 * 256 * 4;                   // 2 MB
    float* scl = (float*)(ws + off); off += 256 * 4;
    float* shf = (float*)(ws + off); off += 256 * 4;

    k_setup<<<1, 320, 0, stream>>>(ei, Ahat);
    k_weights<<<896, 256, 0, stream>>>(W, wconv, Wt, W2t);
    k_gcn<<<BB, 256, 0, stream>>>(x, Ahat, Wt, bgcn, xgcn);
    k_conv<<<dim3(16, 2, 64), 256, 0, stream>>>(xgcn, W2t, bconv, ybuf, partials);
    k_bnstats<<<256, 256, 0, stream>>>(partials, gamma, beta, scl, shf);
    k_apply<<<2048, 256, 0, stream>>>((const unsigned short*)ybuf, out, scl, shf);
}